// Round 5
// baseline (833.389 us; speedup 1.0000x reference)
//
#include <hip/hip_runtime.h>

// Problem constants (from reference setup_inputs)
#define BB 4
#define LL 5
#define CC 256
#define HH 100
#define WW 252
#define HW (HH * WW)      // 25200
#define HW4 (HW / 4)      // 6300
#define NPAIR (BB * LL)   // 20
#define KSEL 1024

// out_kernel tiling: 4 float4-groups per thread, 256 threads/block
#define OG 4
#define OBLK 256
#define OSPAN (OBLK * OG)                     // 1024 groups per block
#define NXBLK ((HW4 + OSPAN - 1) / OSPAN)     // 7

// clang-native 4-float vector: required by __builtin_nontemporal_{load,store}
// (HIP's float4 is a HIP_vector_type class, which the builtin rejects).
typedef float vf4 __attribute__((ext_vector_type(4)));

__device__ __forceinline__ float stable_sigmoid(float d) {
    // Two-branch stable sigmoid, precise expf (verified numerics vs reference).
    if (d >= 0.0f) {
        return 1.0f / (1.0f + expf(-d));
    } else {
        float e = expf(d);
        return e / (1.0f + e);
    }
}

// ---------------------------------------------------------------------------
// Kernel 1: s[b,l,hw] = sigmoid(max_c(psm[b,l,c,hw] - psm[b,0,c,hw])), Cp = 2.
// float4-vectorized; ~6 MB of traffic, trivial.
// ---------------------------------------------------------------------------
__global__ __launch_bounds__(256) void sig_kernel(const float* __restrict__ psm,
                                                  float* __restrict__ s) {
    int i = blockIdx.x * 256 + threadIdx.x;   // over NPAIR*HW4
    if (i >= NPAIR * HW4) return;
    int hw4 = i % HW4;
    int bl  = i / HW4;
    int b   = bl / LL;
    const vf4* p  = (const vf4*)(psm + (size_t)bl * 2 * HW);
    const vf4* pe = (const vf4*)(psm + (size_t)(b * LL) * 2 * HW);
    vf4 a0 = p[hw4];
    vf4 a1 = p[HW4 + hw4];
    vf4 e0 = pe[hw4];
    vf4 e1 = pe[HW4 + hw4];
    vf4 r;
    r.x = stable_sigmoid(fmaxf(a0.x - e0.x, a1.x - e1.x));
    r.y = stable_sigmoid(fmaxf(a0.y - e0.y, a1.y - e1.y));
    r.z = stable_sigmoid(fmaxf(a0.z - e0.z, a1.z - e1.z));
    r.w = stable_sigmoid(fmaxf(a0.w - e0.w, a1.w - e1.w));
    ((vf4*)s)[i] = r;
}

// ---------------------------------------------------------------------------
// Kernel 2: per-(b,l) radix select -> exact K-th largest sigmoid value.
// Keys positive fp32 => uint bit order == float order. 4 passes MSB->LSB.
// Ballot-aggregated histogram: sigmoid outputs concentrate the top byte into
// ~5 bins (exponent in [0,126], values in (0,1)), so plain per-lane atomicAdd
// serializes ~25K LDS atomics/block. The 8-ballot match-mask reduces that to
// one atomic per distinct digit per wave (contention-free within a wave).
// ---------------------------------------------------------------------------
__global__ __launch_bounds__(1024) void select_kernel(const float* __restrict__ s,
                                                      const int* __restrict__ mask,
                                                      float* __restrict__ thresh) {
    int bl = blockIdx.x;
    int l  = bl % LL;
    if (l == 0 || mask[bl] == 0) {
        if (threadIdx.x == 0) thresh[bl] = __int_as_float(0x7f800000); // unused
        return;
    }
    const float* base = s + (size_t)bl * HW;
    __shared__ unsigned hist[256];
    __shared__ unsigned sh_prefix;
    __shared__ int sh_k;
    if (threadIdx.x == 0) { sh_prefix = 0u; sh_k = KSEL; }
    __syncthreads();

    const int HWR = ((HW + 1023) / 1024) * 1024;  // equal trip count all lanes

    for (int sh = 24; sh >= 0; sh -= 8) {
        if (threadIdx.x < 256) hist[threadIdx.x] = 0u;
        __syncthreads();
        unsigned prefix = sh_prefix;
        for (int i = threadIdx.x; i < HWR; i += 1024) {
            bool valid = (i < HW);
            unsigned u = valid ? __float_as_uint(base[i]) : 0u;
            bool ok = valid && ((sh == 24) || (((u ^ prefix) >> (sh + 8)) == 0u));
            unsigned d = (u >> sh) & 255u;
            unsigned long long act = __ballot(ok);
            if (ok) {
                unsigned long long m = act;
                #pragma unroll
                for (int b = 0; b < 8; ++b) {
                    unsigned long long bm = __ballot((d >> b) & 1u);
                    m &= ((d >> b) & 1u) ? bm : ~bm;
                }
                int lane = threadIdx.x & 63;
                int leader = __ffsll((unsigned long long)m) - 1;
                if (lane == leader)
                    atomicAdd(&hist[d], (unsigned)__popcll(m));
            }
        }
        __syncthreads();
        if (threadIdx.x == 0) {
            int kk = sh_k;
            int bin = 255;
            for (; bin > 0; --bin) {
                int c = (int)hist[bin];
                if (kk - c <= 0) break;
                kk -= c;
            }
            sh_prefix = prefix | ((unsigned)bin << sh);
            sh_k = kk;
        }
        __syncthreads();
    }
    if (threadIdx.x == 0) thresh[bl] = __uint_as_float(sh_prefix);
}

// ---------------------------------------------------------------------------
// Kernel 3: dense output. x/out are touch-once streams -> non-temporal
// loads/stores (keep them out of L2/MALL so the reused s slices stay hot and
// stores don't allocate). 4 float4-groups per thread for MLP.
// Grid: x covers HW4 in OSPAN chunks, y = channel, z = (b*L + l).
//   l==0        -> out = x
//   mask[b,l]=0 -> out = 0   (x NOT read)
//   else        -> out_i = (s_i >= t) ? x_i : 0  (x read only if a lane passes;
//                  pass rate is K/HW ~= 4%, so ~85% of groups skip the x load)
// ---------------------------------------------------------------------------
__global__ __launch_bounds__(256) void out_kernel(const float* __restrict__ x,
                                                  const int* __restrict__ mask,
                                                  const float* __restrict__ s,
                                                  const float* __restrict__ thresh,
                                                  float* __restrict__ out) {
    int bl = blockIdx.z;                         // 0..19
    int c  = blockIdx.y;                         // 0..255
    int l  = bl % LL;
    int hw4_0 = blockIdx.x * OSPAN + (int)threadIdx.x;
    size_t cbase = ((size_t)(bl * CC + c)) * HW4;   // float4-group base
    const vf4* x4 = (const vf4*)x;
    vf4* o4 = (vf4*)out;

    if (l == 0) {                                // block-uniform
        #pragma unroll
        for (int j = 0; j < OG; ++j) {
            int hw4 = hw4_0 + j * OBLK;
            if (hw4 < HW4) {
                vf4 v = __builtin_nontemporal_load(&x4[cbase + hw4]);
                __builtin_nontemporal_store(v, &o4[cbase + hw4]);
            }
        }
        return;
    }
    if (mask[bl] == 0) {                         // block-uniform
        vf4 z = (vf4)(0.f);
        #pragma unroll
        for (int j = 0; j < OG; ++j) {
            int hw4 = hw4_0 + j * OBLK;
            if (hw4 < HW4) __builtin_nontemporal_store(z, &o4[cbase + hw4]);
        }
        return;
    }

    float t = thresh[bl];
    const vf4* s4 = (const vf4*)s + (size_t)bl * HW4;  // cached: reused by 256 c-blocks
    #pragma unroll
    for (int j = 0; j < OG; ++j) {
        int hw4 = hw4_0 + j * OBLK;
        if (hw4 >= HW4) continue;
        vf4 sv = s4[hw4];
        bool m0 = sv.x >= t, m1 = sv.y >= t, m2 = sv.z >= t, m3 = sv.w >= t;
        vf4 res = (vf4)(0.f);
        if (m0 | m1 | m2 | m3) {
            vf4 xv = __builtin_nontemporal_load(&x4[cbase + hw4]);
            res.x = m0 ? xv.x : 0.f;
            res.y = m1 ? xv.y : 0.f;
            res.z = m2 ? xv.z : 0.f;
            res.w = m3 ? xv.w : 0.f;
        }
        __builtin_nontemporal_store(res, &o4[cbase + hw4]);
    }
}

// ---------------------------------------------------------------------------
extern "C" void kernel_launch(void* const* d_in, const int* in_sizes, int n_in,
                              void* d_out, int out_size, void* d_ws, size_t ws_size,
                              hipStream_t stream) {
    const float* x   = (const float*)d_in[0];
    const float* psm = (const float*)d_in[1];
    const int* mask  = (const int*)d_in[2];
    float* out = (float*)d_out;

    float* s      = (float*)d_ws;            // NPAIR*HW floats = 2,016,000 B
    float* thresh = s + (size_t)NPAIR * HW;  // 20 floats

    int n_s4 = NPAIR * HW4;
    sig_kernel<<<(n_s4 + 255) / 256, 256, 0, stream>>>(psm, s);
    select_kernel<<<NPAIR, 1024, 0, stream>>>(s, mask, thresh);

    dim3 grid(NXBLK, CC, NPAIR);  // (7, 256, 20)
    out_kernel<<<grid, 256, 0, stream>>>(x, mask, s, thresh, out);
}